// Round 20
// baseline (147.538 us; speedup 1.0000x reference)
//
#include <hip/hip_runtime.h>
#include <math.h>
#include <limits.h>

#define NB 16
#define NC 21
#define NANCH 65536
#define NM 20

#define POS_THR 0.5f
#define NEG_THR 0.4f
#define F_ALPHA 0.25f
#define MIN_POS_TOPK 10
#define NEG_POS_RATIO 3

#define QT 0.125f        // top-10 candidate gather threshold (q >= QT)
#define ST 0.015625f     // neg-cut candidate gather threshold (score < 1/64)
#define QCAP 4096
#define SCAP 4096
#define BCAP 2048        // boundary-bucket cap
#define APT 2
#define IOU_TPB 256

// ---------- K1: pure decode + IoU max/argmax; block 0 zeroes control block ----------
__global__ __launch_bounds__(IOU_TPB)
void k_iou(const float* __restrict__ reg, const float* __restrict__ anchors,
           const float* __restrict__ tb,
           float* __restrict__ miou, int* __restrict__ midx,
           int* __restrict__ zints, float* __restrict__ zsums) {
  if (blockIdx.x == 0) {
    int t = threadIdx.x;
    if (t < 4 * NB + 1) zints[t] = 0;          // pos_cnt, neg_cnt, qcnt, scnt, done
    if (t < 3 * NB) zsums[t] = 0.0f;
  }
  __shared__ float4 tbs4[NM];
  __shared__ float  tarea[NM];
  int b   = blockIdx.x >> 7;           // 128 blocks per image
  int blk = blockIdx.x & 127;
  int n0  = (blk << 9) + threadIdx.x;  // 512 anchors per block
  if (threadIdx.x < NM) {
    float4 t4 = ((const float4*)tb)[b * NM + threadIdx.x];
    tbs4[threadIdx.x] = t4;
    tarea[threadIdx.x] = (t4.z - t4.x) * (t4.w - t4.y);
  }
  __syncthreads();

  float dv[APT][4];
  float areaA[APT];
  #pragma unroll
  for (int j = 0; j < APT; ++j) {
    int n = n0 + j * IOU_TPB;
    float4 a4 = ((const float4*)anchors)[n];
    float aw = a4.z - a4.x, ah = a4.w - a4.y;
    float acx = a4.x + 0.5f * aw, acy = a4.y + 0.5f * ah;
    size_t rb = ((size_t)b * 4) * NANCH + n;
    float rx = reg[rb];
    float ry = reg[rb + (size_t)NANCH];
    float rw = reg[rb + 2 * (size_t)NANCH];
    float rh = reg[rb + 3 * (size_t)NANCH];
    float cx = acx + rx * aw, cy = acy + ry * ah;
    float w = aw * expf(rw), h = ah * expf(rh);
    dv[j][0] = cx - 0.5f * w;
    dv[j][1] = cy - 0.5f * h;
    dv[j][2] = cx + 0.5f * w;
    dv[j][3] = cy + 0.5f * h;
    areaA[j] = (dv[j][2] - dv[j][0]) * (dv[j][3] - dv[j][1]);
  }

  float bI[APT], bU[APT];
  int   bM[APT];
  {
    float4 t = tbs4[0];
    float ab = tarea[0];
    #pragma unroll
    for (int j = 0; j < APT; ++j) {
      float lx = fmaxf(dv[j][0], t.x), ly = fmaxf(dv[j][1], t.y);
      float rx2 = fminf(dv[j][2], t.z), ry2 = fminf(dv[j][3], t.w);
      float iw = fmaxf(rx2 - lx, 0.0f), ih = fmaxf(ry2 - ly, 0.0f);
      float inter = iw * ih;
      bI[j] = inter;
      bU[j] = areaA[j] + ab - inter;
      bM[j] = 0;
    }
  }
  #pragma unroll
  for (int m = 1; m < NM; ++m) {
    float4 t = tbs4[m];
    float ab = tarea[m];
    #pragma unroll
    for (int j = 0; j < APT; ++j) {
      float lx = fmaxf(dv[j][0], t.x), ly = fmaxf(dv[j][1], t.y);
      float rx2 = fminf(dv[j][2], t.z), ry2 = fminf(dv[j][3], t.w);
      float iw = fmaxf(rx2 - lx, 0.0f), ih = fmaxf(ry2 - ly, 0.0f);
      float inter = iw * ih;
      float uni = areaA[j] + ab - inter;
      // inter/uni > bI/bU  <=>  inter*bU > bI*uni (both unions > 0)
      if (inter * bU[j] > bI[j] * uni) { bI[j] = inter; bU[j] = uni; bM[j] = m; }
    }
  }

  #pragma unroll
  for (int j = 0; j < APT; ++j) {
    int n = n0 + j * IOU_TPB;
    size_t idx = (size_t)b * NANCH + n;
    miou[idx] = bI[j] / fmaxf(bU[j], 1e-7f);   // IEEE, matches reference
    midx[idx] = bM[j];
  }
}

// wave-aggregated append into an LDS list: one LDS atomic per wave
__device__ __forceinline__ void wave_append_lds(bool want, int lane,
                                                int* cnt, unsigned* kb, int* ki,
                                                unsigned bits, int n) {
  unsigned long long m = __ballot(want);
  if (!m) return;
  int leader = __ffsll((long long)m) - 1;
  int base = 0;
  if (lane == leader) base = atomicAdd(cnt, __popcll(m));
  base = __shfl(base, leader, 64);
  if (want) {
    int slot = base + __popcll(m & ((1ULL << lane) - 1ULL));
    kb[slot] = bits; ki[slot] = n;    // slot < 1024 guaranteed (block covers 1024 anchors)
  }
}

// ---------- K2: counts + candidate gathers (block-aggregated) ----------
__global__ __launch_bounds__(1024)
void k_gather(const float* __restrict__ miou, const float* __restrict__ scores,
              int* __restrict__ pos_cnt, int* __restrict__ neg_cnt,
              unsigned* __restrict__ qcb, int* __restrict__ qci, int* __restrict__ qcnt,
              unsigned* __restrict__ scb, int* __restrict__ sci, int* __restrict__ scnt) {
  __shared__ unsigned lqB[1024];
  __shared__ int      lqI[1024];
  __shared__ unsigned lsB[1024];
  __shared__ int      lsI[1024];
  __shared__ int lqc, lsc, qbase, sbase;
  __shared__ int redp[16], redn[16];
  int b = blockIdx.x >> 6;                        // 64 blocks per image
  int n = ((blockIdx.x & 63) << 10) | threadIdx.x;
  if (threadIdx.x == 0) { lqc = 0; lsc = 0; }
  __syncthreads();

  size_t idx = (size_t)b * NANCH + n;
  float q = miou[idx];
  float s = scores[idx];
  bool p  = (q >= POS_THR);
  bool ng = (q < NEG_THR);
  int lane = threadIdx.x & 63;
  int wid  = threadIdx.x >> 6;
  int cp = __popcll(__ballot(p));
  int cn = __popcll(__ballot(ng));
  if (lane == 0) { redp[wid] = cp; redn[wid] = cn; }

  wave_append_lds(q >= QT, lane, &lqc, lqB, lqI, __float_as_uint(q), n);
  wave_append_lds(ng && s < ST, lane, &lsc, lsB, lsI, __float_as_uint(s), n);
  __syncthreads();

  if (threadIdx.x == 0) {
    int tp = 0, tn = 0;
    for (int w = 0; w < 16; ++w) { tp += redp[w]; tn += redn[w]; }
    if (tp) atomicAdd(&pos_cnt[b], tp);
    if (tn) atomicAdd(&neg_cnt[b], tn);
    qbase = lqc ? atomicAdd(&qcnt[b], lqc) : 0;
    sbase = lsc ? atomicAdd(&scnt[b], lsc) : 0;
  }
  __syncthreads();

  for (int j = threadIdx.x; j < lqc; j += 1024) {
    int slot = qbase + j;
    if (slot < QCAP) {
      qcb[(size_t)b * QCAP + slot] = lqB[j];
      qci[(size_t)b * QCAP + slot] = lqI[j];
    }
  }
  for (int j = threadIdx.x; j < lsc; j += 1024) {
    int slot = sbase + j;
    if (slot < SCAP) {
      scb[(size_t)b * SCAP + slot] = lsB[j];
      sci[(size_t)b * SCAP + slot] = lsI[j];
    }
  }
}

// 10x iterative argmax (bits desc, idx asc) over cB/cI[0..E), 1024 threads
__device__ __forceinline__ void argmax10(unsigned* cB, int* cI, int E,
                                         int* top10_out) {
  __shared__ unsigned wv[16];
  __shared__ int      wi_[16], wsl[16];
  __shared__ int      sel[MIN_POS_TOPK];
  int lane = threadIdx.x & 63;
  int wid  = threadIdx.x >> 6;
  for (int it = 0; it < MIN_POS_TOPK; ++it) {
    unsigned bb = 0u; int bi = INT_MAX, bs = -1;
    for (int j = threadIdx.x; j < E; j += 1024) {
      unsigned v = cB[j];
      if (v > bb || (v == bb && cI[j] < bi)) { bb = v; bi = cI[j]; bs = j; }
    }
    #pragma unroll
    for (int m = 32; m >= 1; m >>= 1) {
      unsigned ov = __shfl_xor(bb, m, 64);
      int oi = __shfl_xor(bi, m, 64);
      int os = __shfl_xor(bs, m, 64);
      if (ov > bb || (ov == bb && oi < bi)) { bb = ov; bi = oi; bs = os; }
    }
    if (lane == 0) { wv[wid] = bb; wi_[wid] = bi; wsl[wid] = bs; }
    __syncthreads();
    if (threadIdx.x == 0) {
      unsigned eb = 0u; int ei = INT_MAX, es = -1;
      for (int w = 0; w < 16; ++w) {
        if (wv[w] > eb || (wv[w] == eb && wi_[w] < ei)) { eb = wv[w]; ei = wi_[w]; es = wsl[w]; }
      }
      sel[it] = ei;
      cB[es] = 0u;                      // remove winner (real bits always > 0)
    }
    __syncthreads();
  }
  if (threadIdx.x < MIN_POS_TOPK) top10_out[threadIdx.x] = sel[threadIdx.x];
}

// ---------- K3: blocks 0..15 top-10 (inline rescue), 16..31 neg cut (inline rescue) ----------
__global__ __launch_bounds__(1024)
void k_sel(const unsigned* __restrict__ qcb, const int* __restrict__ qci,
           const int* __restrict__ qcnt,
           const unsigned* __restrict__ scb, const int* __restrict__ sci,
           const int* __restrict__ scnt,
           const int* __restrict__ pos_cnt, const int* __restrict__ neg_cnt,
           const float* __restrict__ miou, const float* __restrict__ scores,
           int* __restrict__ num_pos, int* __restrict__ use_fb,
           int* __restrict__ subsample, int* __restrict__ total_samples,
           int* __restrict__ top10,
           unsigned* __restrict__ vbits_out, int* __restrict__ idx_cut) {
  __shared__ unsigned cB[QCAP];
  __shared__ int      cI[QCAP];
  if (blockIdx.x < NB) {
    // ---------- top-10 path ----------
    int b = blockIdx.x;
    int pc = pos_cnt[b], nc = neg_cnt[b];
    int fb = (pc < MIN_POS_TOPK) ? 1 : 0;
    int np = fb ? MIN_POS_TOPK : pc;
    int k = NEG_POS_RATIO * np;
    int sub = (nc > k) ? 1 : 0;
    if (threadIdx.x == 0) {
      num_pos[b] = np; use_fb[b] = fb; subsample[b] = sub;
      total_samples[b] = sub ? (np + k) : (np + nc);
    }
    if (!fb) return;                       // top10 unused by k_loss
    int E = qcnt[b];
    if (E >= MIN_POS_TOPK && E <= QCAP) {
      for (int j = threadIdx.x; j < E; j += 1024) {
        cB[j] = qcb[(size_t)b * QCAP + j];   // all > 0 (q >= QT)
        cI[j] = qci[(size_t)b * QCAP + j];
      }
      __syncthreads();
      argmax10(cB, cI, E, top10 + b * MIN_POS_TOPK);
      return;
    }
    // ---------- inline rescue: adaptive 64-bin re-gather ----------
    const float* mi = miou + (size_t)b * NANCH;
    __shared__ unsigned qh[64];
    __shared__ int s_thr, s_cnt, s_ok;
    if (threadIdx.x < 64) qh[threadIdx.x] = 0u;
    if (threadIdx.x == 0) { s_cnt = 0; s_ok = 0; }
    __syncthreads();
    for (int n = threadIdx.x; n < NANCH; n += 1024) {
      float q = mi[n];
      if (q >= QT) {
        unsigned bin = (unsigned)(q * 64.0f);
        if (bin > 63u) bin = 63u;
        atomicAdd(&qh[bin], 1u);
      }
    }
    __syncthreads();
    if (threadIdx.x == 0) {
      unsigned cum = 0; int t = -1;
      for (int i = 63; i >= 8; --i) {          // largest t with suffix >= 10
        cum += qh[i];
        if (cum >= (unsigned)MIN_POS_TOPK) { t = i; break; }
      }
      if (t < 0) t = 8;
      unsigned c = 0;
      for (int i = t; i < 64; ++i) c += qh[i];
      s_thr = t;
      s_ok = (c >= (unsigned)MIN_POS_TOPK && c <= (unsigned)QCAP) ? 1 : 0;
    }
    __syncthreads();
    if (s_ok) {
      int t = s_thr;
      for (int n = threadIdx.x; n < NANCH; n += 1024) {
        float q = mi[n];
        if (q >= QT) {
          unsigned bin = (unsigned)(q * 64.0f);
          if (bin > 63u) bin = 63u;
          if ((int)bin >= t) {
            int slot = atomicAdd(&s_cnt, 1);
            if (slot < QCAP) {
              cB[slot] = __float_as_uint(q);
              cI[slot] = n;
            }
          }
        }
      }
      __syncthreads();
      int E2 = s_cnt < QCAP ? s_cnt : QCAP;
      argmax10(cB, cI, E2, top10 + b * MIN_POS_TOPK);
    } else {
      // ultra-fallback (structurally ~never): exact 10-iteration full scan
      __shared__ float fsv[16];
      __shared__ int   fsi[16];
      __shared__ int   fsel[MIN_POS_TOPK];
      int lane = threadIdx.x & 63;
      int wid  = threadIdx.x >> 6;
      for (int it = 0; it < MIN_POS_TOPK; ++it) {
        float bv = -1.0f; int bi = NANCH;
        for (int n = threadIdx.x; n < NANCH; n += 1024) {
          bool skip = false;
          for (int s2 = 0; s2 < it; ++s2) if (fsel[s2] == n) skip = true;
          if (skip) continue;
          float v = mi[n];
          if (v > bv || (v == bv && n < bi)) { bv = v; bi = n; }
        }
        #pragma unroll
        for (int m = 32; m >= 1; m >>= 1) {
          float ov = __shfl_xor(bv, m, 64);
          int   oi = __shfl_xor(bi, m, 64);
          if (ov > bv || (ov == bv && oi < bi)) { bv = ov; bi = oi; }
        }
        if (lane == 0) { fsv[wid] = bv; fsi[wid] = bi; }
        __syncthreads();
        if (threadIdx.x == 0) {
          float bb = -1.0f; int bj = NANCH;
          for (int w = 0; w < 16; ++w)
            if (fsv[w] > bb || (fsv[w] == bb && fsi[w] < bj)) { bb = fsv[w]; bj = fsi[w]; }
          fsel[it] = bj;
        }
        __syncthreads();
      }
      if (threadIdx.x < MIN_POS_TOPK) top10[b * MIN_POS_TOPK + threadIdx.x] = fsel[threadIdx.x];
    }
  } else {
    // ---------- neg-cut path ----------
    __shared__ unsigned hist[256];
    __shared__ unsigned* bbB;            // aliases into cB/cI space
    __shared__ int s_bkt, s_below, s_cnt, s_fail;
    unsigned* BB = cB;                   // boundary bits list (cap BCAP)
    int*      BI = cI;
    int b = blockIdx.x - NB;
    int pc = pos_cnt[b], nc = neg_cnt[b];
    int np = (pc < MIN_POS_TOPK) ? MIN_POS_TOPK : pc;
    int k = NEG_POS_RATIO * np;
    if (nc <= k) {
      if (threadIdx.x == 0) { vbits_out[b] = 0u; idx_cut[b] = -1; }
      return;
    }
    int E = scnt[b];
    bool cand_ok = (E >= k && E <= SCAP);
    if (threadIdx.x == 0) s_fail = 0;
    if (cand_ok) {
      // exact neg cut via 256-bin sub-hist of [0, ST): s*2^14 exact & monotone
      if (threadIdx.x < 256) hist[threadIdx.x] = 0u;
      if (threadIdx.x == 0) s_cnt = 0;
      __syncthreads();
      for (int j = threadIdx.x; j < E; j += 1024) {
        float s = __uint_as_float(scb[(size_t)b * SCAP + j]);
        unsigned bin = (unsigned)(s * 16384.0f);
        atomicAdd(&hist[bin > 255u ? 255u : bin], 1u);
      }
      __syncthreads();
      if (threadIdx.x == 0) {
        unsigned cum = 0; int bkt = 255;
        for (int t = 0; t < 256; ++t) {
          if (cum + hist[t] >= (unsigned)k) { bkt = t; break; }
          cum += hist[t];
        }
        s_bkt = bkt; s_below = (int)cum;
      }
      __syncthreads();
      int bkt = s_bkt;
      for (int j = threadIdx.x; j < E; j += 1024) {
        unsigned sb = scb[(size_t)b * SCAP + j];
        float s = __uint_as_float(sb);
        unsigned bin = (unsigned)(s * 16384.0f);
        if ((int)(bin > 255u ? 255u : bin) == bkt) {
          int slot = atomicAdd(&s_cnt, 1);
          if (slot < BCAP) { BB[slot] = sb; BI[slot] = sci[(size_t)b * SCAP + j]; }
        }
      }
      __syncthreads();
      int cnt = s_cnt;
      int r = k - s_below;
      if (cnt > BCAP || r < 1 || r > cnt) {
        if (threadIdx.x == 0) s_fail = 1;
      } else {
        for (int e = threadIdx.x; e < cnt; e += 1024) {
          unsigned mb = BB[e]; int mi_ = BI[e];
          int rank = 0;
          for (int j = 0; j < cnt; ++j) {
            unsigned ob = BB[j]; int oi = BI[j];
            rank += (ob < mb || (ob == mb && oi < mi_)) ? 1 : 0;
          }
          if (rank == r - 1) { vbits_out[b] = mb; idx_cut[b] = mi_; }
        }
      }
      __syncthreads();
      if (!s_fail) return;
    }
    // ---------- inline rescue: full-image 256-bin hist ----------
    const float* mi = miou + (size_t)b * NANCH;
    const float* sc = scores + (size_t)b * NANCH;
    if (threadIdx.x < 256) hist[threadIdx.x] = 0u;
    if (threadIdx.x == 0) s_cnt = 0;
    __syncthreads();
    for (int n = threadIdx.x; n < NANCH; n += 1024) {
      if (mi[n] < NEG_THR) {
        unsigned bin = (unsigned)(sc[n] * 256.0f);
        if (bin > 255u) bin = 255u;
        atomicAdd(&hist[bin], 1u);
      }
    }
    __syncthreads();
    if (threadIdx.x == 0) {
      unsigned cum = 0; int bkt = 255;
      for (int t = 0; t < 256; ++t) {
        if (cum + hist[t] >= (unsigned)k) { bkt = t; break; }
        cum += hist[t];
      }
      s_bkt = bkt; s_below = (int)cum;
    }
    __syncthreads();
    int bkt = s_bkt;
    for (int n = threadIdx.x; n < NANCH; n += 1024) {
      if (mi[n] < NEG_THR) {
        float s = sc[n];
        unsigned bin = (unsigned)(s * 256.0f);
        if (bin > 255u) bin = 255u;
        if ((int)bin == bkt) {
          int slot = atomicAdd(&s_cnt, 1);
          if (slot < BCAP) {
            BB[slot] = __float_as_uint(s);
            BI[slot] = n;
          }
        }
      }
    }
    __syncthreads();
    int cnt = s_cnt < BCAP ? s_cnt : BCAP;
    int r = k - s_below;
    if (threadIdx.x == 0 && (r < 1 || r > cnt)) {   // overflow safety (never expected)
      vbits_out[b] = 0xFFFFFFFFu; idx_cut[b] = NANCH;
    }
    for (int e = threadIdx.x; e < cnt; e += 1024) {
      unsigned mb = BB[e]; int mi_ = BI[e];
      int rank = 0;
      for (int j = 0; j < cnt; ++j) {
        unsigned ob = BB[j]; int oi = BI[j];
        rank += (ob < mb || (ob == mb && oi < mi_)) ? 1 : 0;
      }
      if (rank == r - 1) { vbits_out[b] = mb; idx_cut[b] = mi_; }
    }
  }
}

// ---------- K4: per-anchor loss accumulation + last-block finalize ----------
__global__ __launch_bounds__(256)
void k_loss(const float* __restrict__ cls, const float* __restrict__ reg,
            const float* __restrict__ anchors, const float* __restrict__ tb,
            const int* __restrict__ tl, const float* __restrict__ scores,
            const float* __restrict__ miou, const int* __restrict__ midx,
            const int* __restrict__ use_fb, const int* __restrict__ top10,
            const int* __restrict__ subsample, const unsigned* __restrict__ vbits,
            const int* __restrict__ idx_cut,
            float* __restrict__ sums /* [NB][3] : pos, neg, reg */,
            const int* __restrict__ total_samples, const int* __restrict__ num_pos,
            int* __restrict__ done_cnt, float* __restrict__ out) {
  int b = blockIdx.x >> 8;
  int n = ((blockIdx.x & 255) << 8) | threadIdx.x;
  __shared__ int s_top10[MIN_POS_TOPK];
  __shared__ int s_usefb, s_sub, s_cut;
  __shared__ unsigned s_vb;
  __shared__ float accp, accn, accr;
  __shared__ int s_last;
  if (threadIdx.x < MIN_POS_TOPK) s_top10[threadIdx.x] = top10[b * MIN_POS_TOPK + threadIdx.x];
  if (threadIdx.x == 0) {
    s_usefb = use_fb[b]; s_sub = subsample[b]; s_cut = idx_cut[b]; s_vb = vbits[b];
    accp = 0.0f; accn = 0.0f; accr = 0.0f;
  }
  __syncthreads();

  size_t idx = (size_t)b * NANCH + n;
  float mi = miou[idx];

  bool pos;
  if (s_usefb) {
    pos = false;
    #pragma unroll
    for (int i = 0; i < MIN_POS_TOPK; ++i) pos |= (s_top10[i] == n);
  } else {
    pos = (mi >= POS_THR);
  }
  bool neg = (mi < NEG_THR);
  bool nsel = false;
  if (neg) {
    if (!s_sub) nsel = true;
    else {
      unsigned sb = __float_as_uint(scores[idx]);
      nsel = (sb < s_vb) || (sb == s_vb && n <= s_cut);
    }
  }

  float cp = 0.0f, cn = 0.0f, rg = 0.0f;
  if (pos || nsel) {
    int mx = 0, t = 0;
    if (pos) { mx = midx[idx]; t = tl[b * NM + mx]; }
    size_t cb = ((size_t)b * NC) * NANCH + n;
    float mxl = -3.0e38f, l0 = 0.0f, lt = 0.0f;
    for (int c = 0; c < NC; ++c) {
      float l = cls[cb + (size_t)c * NANCH];
      if (c == 0) l0 = l;
      if (c == t) lt = l;
      mxl = fmaxf(mxl, l);
    }
    float se = 0.0f;
    for (int c = 0; c < NC; ++c) {
      float l = cls[cb + (size_t)c * NANCH];
      se += expf(l - mxl);
    }
    float lse = mxl + logf(se);
    if (nsel) {
      float ce = lse - l0;
      float pt = expf(-ce);
      float om = 1.0f - pt;
      cn = F_ALPHA * om * om * ce;
    }
    if (pos) {
      float ce = lse - lt;
      float pt = expf(-ce);
      float om = 1.0f - pt;
      cp = F_ALPHA * om * om * ce;
      // decode + GIoU vs matched GT
      const float4 a4 = ((const float4*)anchors)[n];
      float aw = a4.z - a4.x, ah = a4.w - a4.y;
      float acx = a4.x + 0.5f * aw, acy = a4.y + 0.5f * ah;
      size_t rb = ((size_t)b * 4) * NANCH + n;
      float rx = reg[rb];
      float ry = reg[rb + (size_t)NANCH];
      float rw = reg[rb + 2 * (size_t)NANCH];
      float rh = reg[rb + 3 * (size_t)NANCH];
      float ccx = acx + rx * aw, ccy = acy + ry * ah;
      float w = aw * expf(rw), h = ah * expf(rh);
      float d0 = ccx - 0.5f * w, d1 = ccy - 0.5f * h;
      float d2 = ccx + 0.5f * w, d3 = ccy + 0.5f * h;
      const float* g = tb + ((size_t)b * NM + mx) * 4;
      float gx1 = g[0], gy1 = g[1], gx2 = g[2], gy2 = g[3];
      float area_a = (d2 - d0) * (d3 - d1);
      float area_b = (gx2 - gx1) * (gy2 - gy1);
      float lx = fmaxf(d0, gx1), ly = fmaxf(d1, gy1);
      float rx2 = fminf(d2, gx2), ry2 = fminf(d3, gy2);
      float iw = fmaxf(rx2 - lx, 0.0f), ih = fmaxf(ry2 - ly, 0.0f);
      float inter = iw * ih;
      float uni = area_a + area_b - inter;
      float iou = inter / fmaxf(uni, 1e-7f);
      float ex1 = fminf(d0, gx1), ey1 = fminf(d1, gy1);
      float ex2 = fmaxf(d2, gx2), ey2 = fmaxf(d3, gy2);
      float ew = fmaxf(ex2 - ex1, 0.0f), eh = fmaxf(ey2 - ey1, 0.0f);
      float enc = ew * eh;
      float giou = iou - (enc - uni) / fmaxf(enc, 1e-7f);
      rg = 1.0f - giou;
    }
  }

  if (cp != 0.0f) atomicAdd(&accp, cp);
  if (cn != 0.0f) atomicAdd(&accn, cn);
  if (rg != 0.0f) atomicAdd(&accr, rg);
  __syncthreads();
  if (threadIdx.x == 0) {
    if (accp != 0.0f) atomicAdd(&sums[b * 3 + 0], accp);
    if (accn != 0.0f) atomicAdd(&sums[b * 3 + 1], accn);
    if (accr != 0.0f) atomicAdd(&sums[b * 3 + 2], accr);
    __threadfence();
    int done = atomicAdd(done_cnt, 1);
    s_last = (done == (int)gridDim.x - 1) ? 1 : 0;
  }
  __syncthreads();

  if (s_last) {
    // last block: reduce per-image sums into the scalar loss.
    // sums written by atomics this kernel -> read via atomicAdd(p, 0) for
    // cross-XCD coherence; total_samples/num_pos written last kernel (visible).
    int t = threadIdx.x;
    if (t < 64) {
      float cm = 0.0f, rm = 0.0f;
      if (t < NB) {
        int ts = total_samples[t]; if (ts < 1) ts = 1;
        int np = num_pos[t]; if (np < 1) np = 1;
        float s0 = atomicAdd(&sums[t * 3 + 0], 0.0f);
        float s1 = atomicAdd(&sums[t * 3 + 1], 0.0f);
        float s2 = atomicAdd(&sums[t * 3 + 2], 0.0f);
        cm = (s0 + s1) / (float)ts;
        rm = s2 / (float)np;
      }
      #pragma unroll
      for (int m = 8; m >= 1; m >>= 1) {
        cm += __shfl_down(cm, m, 64);
        rm += __shfl_down(rm, m, 64);
      }
      if (t == 0) out[0] = cm / (float)NB + rm / (float)NB;
    }
  }
}

extern "C" void kernel_launch(void* const* d_in, const int* in_sizes, int n_in,
                              void* d_out, int out_size, void* d_ws, size_t ws_size,
                              hipStream_t stream) {
  const float* cls     = (const float*)d_in[0];
  const float* reg     = (const float*)d_in[1];
  const float* anchors = (const float*)d_in[2];
  const float* tb      = (const float*)d_in[3];
  const int*   tl      = (const int*)d_in[4];
  const float* scores  = (const float*)d_in[5];
  float* out = (float*)d_out;

  char* ws = (char*)d_ws;
  size_t off = 0;
  float* miou = (float*)(ws + off);            off += (size_t)4 * NB * NANCH;
  int*   midx = (int*)(ws + off);              off += (size_t)4 * NB * NANCH;
  unsigned* qcb = (unsigned*)(ws + off);       off += (size_t)4 * NB * QCAP;
  int*   qci = (int*)(ws + off);               off += (size_t)4 * NB * QCAP;
  unsigned* scb = (unsigned*)(ws + off);       off += (size_t)4 * NB * SCAP;
  int*   sci = (int*)(ws + off);               off += (size_t)4 * NB * SCAP;
  int* scal = (int*)(ws + off);
  // zeroed by k_iou block 0: first 4*NB+1 ints + sums (3*NB floats)
  int* pos_cnt  = scal;
  int* neg_cnt  = scal + NB;
  int* qcnt     = scal + 2 * NB;
  int* scnt     = scal + 3 * NB;
  int* done_cnt = scal + 4 * NB;       // 1 int
  int* num_pos       = scal + 4 * NB + 1;
  int* use_fb        = scal + 5 * NB + 1;
  int* subsample     = scal + 6 * NB + 1;
  int* idx_cut       = scal + 7 * NB + 1;
  unsigned* vbits    = (unsigned*)(scal + 8 * NB + 1);
  int* total_samples = scal + 9 * NB + 1;
  int* top10         = scal + 10 * NB + 1;                     // NB*10
  float* sums        = (float*)(scal + 10 * NB + 1 + MIN_POS_TOPK * NB); // NB*3

  k_iou<<<NB * 128, IOU_TPB, 0, stream>>>(reg, anchors, tb, miou, midx,
                                          scal, sums);
  k_gather<<<NB * 64, 1024, 0, stream>>>(miou, scores, pos_cnt, neg_cnt,
                                         qcb, qci, qcnt, scb, sci, scnt);
  k_sel<<<2 * NB, 1024, 0, stream>>>(qcb, qci, qcnt, scb, sci, scnt,
                                     pos_cnt, neg_cnt, miou, scores,
                                     num_pos, use_fb, subsample, total_samples,
                                     top10, vbits, idx_cut);
  k_loss<<<NB * 256, 256, 0, stream>>>(cls, reg, anchors, tb, tl, scores,
                                       miou, midx, use_fb, top10, subsample,
                                       vbits, idx_cut, sums,
                                       total_samples, num_pos, done_cnt, out);
}

// Round 22
// 78.475 us; speedup vs baseline: 1.8801x; 1.8801x over previous
//
#include <hip/hip_runtime.h>
#include <math.h>
#include <limits.h>

#define NB 16
#define NC 21
#define NANCH 65536
#define NM 20

#define POS_THR 0.5f
#define NEG_THR 0.4f
#define F_ALPHA 0.25f
#define MIN_POS_TOPK 10
#define NEG_POS_RATIO 3

#define QT 0.125f        // top-10 candidate gather threshold (q >= QT)
#define ST 0.015625f     // neg-cut candidate gather threshold (score < 1/64)
#define QCAP 4096
#define SCAP 4096
#define BCAP 2048        // boundary-bucket cap
#define APT 2
#define IOU_TPB 256

// ---------- K1: pure decode + IoU max/argmax; block 0 zeroes control block ----------
__global__ __launch_bounds__(IOU_TPB)
void k_iou(const float* __restrict__ reg, const float* __restrict__ anchors,
           const float* __restrict__ tb,
           float* __restrict__ miou, int* __restrict__ midx,
           int* __restrict__ zints, float* __restrict__ zsums) {
  if (blockIdx.x == 0) {
    int t = threadIdx.x;
    if (t < 4 * NB) zints[t] = 0;              // pos_cnt, neg_cnt, qcnt, scnt
    if (t < 3 * NB) zsums[t] = 0.0f;
  }
  __shared__ float4 tbs4[NM];
  __shared__ float  tarea[NM];
  int b   = blockIdx.x >> 7;           // 128 blocks per image
  int blk = blockIdx.x & 127;
  int n0  = (blk << 9) + threadIdx.x;  // 512 anchors per block
  if (threadIdx.x < NM) {
    float4 t4 = ((const float4*)tb)[b * NM + threadIdx.x];
    tbs4[threadIdx.x] = t4;
    tarea[threadIdx.x] = (t4.z - t4.x) * (t4.w - t4.y);
  }
  __syncthreads();

  float dv[APT][4];
  float areaA[APT];
  #pragma unroll
  for (int j = 0; j < APT; ++j) {
    int n = n0 + j * IOU_TPB;
    float4 a4 = ((const float4*)anchors)[n];
    float aw = a4.z - a4.x, ah = a4.w - a4.y;
    float acx = a4.x + 0.5f * aw, acy = a4.y + 0.5f * ah;
    size_t rb = ((size_t)b * 4) * NANCH + n;
    float rx = reg[rb];
    float ry = reg[rb + (size_t)NANCH];
    float rw = reg[rb + 2 * (size_t)NANCH];
    float rh = reg[rb + 3 * (size_t)NANCH];
    float cx = acx + rx * aw, cy = acy + ry * ah;
    float w = aw * expf(rw), h = ah * expf(rh);
    dv[j][0] = cx - 0.5f * w;
    dv[j][1] = cy - 0.5f * h;
    dv[j][2] = cx + 0.5f * w;
    dv[j][3] = cy + 0.5f * h;
    areaA[j] = (dv[j][2] - dv[j][0]) * (dv[j][3] - dv[j][1]);
  }

  float bI[APT], bU[APT];
  int   bM[APT];
  {
    float4 t = tbs4[0];
    float ab = tarea[0];
    #pragma unroll
    for (int j = 0; j < APT; ++j) {
      float lx = fmaxf(dv[j][0], t.x), ly = fmaxf(dv[j][1], t.y);
      float rx2 = fminf(dv[j][2], t.z), ry2 = fminf(dv[j][3], t.w);
      float iw = fmaxf(rx2 - lx, 0.0f), ih = fmaxf(ry2 - ly, 0.0f);
      float inter = iw * ih;
      bI[j] = inter;
      bU[j] = areaA[j] + ab - inter;
      bM[j] = 0;
    }
  }
  #pragma unroll
  for (int m = 1; m < NM; ++m) {
    float4 t = tbs4[m];
    float ab = tarea[m];
    #pragma unroll
    for (int j = 0; j < APT; ++j) {
      float lx = fmaxf(dv[j][0], t.x), ly = fmaxf(dv[j][1], t.y);
      float rx2 = fminf(dv[j][2], t.z), ry2 = fminf(dv[j][3], t.w);
      float iw = fmaxf(rx2 - lx, 0.0f), ih = fmaxf(ry2 - ly, 0.0f);
      float inter = iw * ih;
      float uni = areaA[j] + ab - inter;
      // inter/uni > bI/bU  <=>  inter*bU > bI*uni (both unions > 0)
      if (inter * bU[j] > bI[j] * uni) { bI[j] = inter; bU[j] = uni; bM[j] = m; }
    }
  }

  #pragma unroll
  for (int j = 0; j < APT; ++j) {
    int n = n0 + j * IOU_TPB;
    size_t idx = (size_t)b * NANCH + n;
    miou[idx] = bI[j] / fmaxf(bU[j], 1e-7f);   // IEEE, matches reference
    midx[idx] = bM[j];
  }
}

// wave-aggregated append into an LDS list: one LDS atomic per wave
__device__ __forceinline__ void wave_append_lds(bool want, int lane,
                                                int* cnt, unsigned* kb, int* ki,
                                                unsigned bits, int n) {
  unsigned long long m = __ballot(want);
  if (!m) return;
  int leader = __ffsll((long long)m) - 1;
  int base = 0;
  if (lane == leader) base = atomicAdd(cnt, __popcll(m));
  base = __shfl(base, leader, 64);
  if (want) {
    int slot = base + __popcll(m & ((1ULL << lane) - 1ULL));
    kb[slot] = bits; ki[slot] = n;    // slot < 1024 guaranteed (block covers 1024 anchors)
  }
}

// ---------- K2: counts + candidate gathers (block-aggregated) ----------
__global__ __launch_bounds__(1024)
void k_gather(const float* __restrict__ miou, const float* __restrict__ scores,
              int* __restrict__ pos_cnt, int* __restrict__ neg_cnt,
              unsigned* __restrict__ qcb, int* __restrict__ qci, int* __restrict__ qcnt,
              unsigned* __restrict__ scb, int* __restrict__ sci, int* __restrict__ scnt) {
  __shared__ unsigned lqB[1024];
  __shared__ int      lqI[1024];
  __shared__ unsigned lsB[1024];
  __shared__ int      lsI[1024];
  __shared__ int lqc, lsc, qbase, sbase;
  __shared__ int redp[16], redn[16];
  int b = blockIdx.x >> 6;                        // 64 blocks per image
  int n = ((blockIdx.x & 63) << 10) | threadIdx.x;
  if (threadIdx.x == 0) { lqc = 0; lsc = 0; }
  __syncthreads();

  size_t idx = (size_t)b * NANCH + n;
  float q = miou[idx];
  float s = scores[idx];
  bool p  = (q >= POS_THR);
  bool ng = (q < NEG_THR);
  int lane = threadIdx.x & 63;
  int wid  = threadIdx.x >> 6;
  int cp = __popcll(__ballot(p));
  int cn = __popcll(__ballot(ng));
  if (lane == 0) { redp[wid] = cp; redn[wid] = cn; }

  wave_append_lds(q >= QT, lane, &lqc, lqB, lqI, __float_as_uint(q), n);
  wave_append_lds(ng && s < ST, lane, &lsc, lsB, lsI, __float_as_uint(s), n);
  __syncthreads();

  if (threadIdx.x == 0) {
    int tp = 0, tn = 0;
    for (int w = 0; w < 16; ++w) { tp += redp[w]; tn += redn[w]; }
    if (tp) atomicAdd(&pos_cnt[b], tp);
    if (tn) atomicAdd(&neg_cnt[b], tn);
    qbase = lqc ? atomicAdd(&qcnt[b], lqc) : 0;
    sbase = lsc ? atomicAdd(&scnt[b], lsc) : 0;
  }
  __syncthreads();

  for (int j = threadIdx.x; j < lqc; j += 1024) {
    int slot = qbase + j;
    if (slot < QCAP) {
      qcb[(size_t)b * QCAP + slot] = lqB[j];
      qci[(size_t)b * QCAP + slot] = lqI[j];
    }
  }
  for (int j = threadIdx.x; j < lsc; j += 1024) {
    int slot = sbase + j;
    if (slot < SCAP) {
      scb[(size_t)b * SCAP + slot] = lsB[j];
      sci[(size_t)b * SCAP + slot] = lsI[j];
    }
  }
}

// 10x iterative argmax (bits desc, idx asc) over cB/cI[0..E), 1024 threads
__device__ __forceinline__ void argmax10(unsigned* cB, int* cI, int E,
                                         int* top10_out) {
  __shared__ unsigned wv[16];
  __shared__ int      wi_[16], wsl[16];
  __shared__ int      sel[MIN_POS_TOPK];
  int lane = threadIdx.x & 63;
  int wid  = threadIdx.x >> 6;
  for (int it = 0; it < MIN_POS_TOPK; ++it) {
    unsigned bb = 0u; int bi = INT_MAX, bs = -1;
    for (int j = threadIdx.x; j < E; j += 1024) {
      unsigned v = cB[j];
      if (v > bb || (v == bb && cI[j] < bi)) { bb = v; bi = cI[j]; bs = j; }
    }
    #pragma unroll
    for (int m = 32; m >= 1; m >>= 1) {
      unsigned ov = __shfl_xor(bb, m, 64);
      int oi = __shfl_xor(bi, m, 64);
      int os = __shfl_xor(bs, m, 64);
      if (ov > bb || (ov == bb && oi < bi)) { bb = ov; bi = oi; bs = os; }
    }
    if (lane == 0) { wv[wid] = bb; wi_[wid] = bi; wsl[wid] = bs; }
    __syncthreads();
    if (threadIdx.x == 0) {
      unsigned eb = 0u; int ei = INT_MAX, es = -1;
      for (int w = 0; w < 16; ++w) {
        if (wv[w] > eb || (wv[w] == eb && wi_[w] < ei)) { eb = wv[w]; ei = wi_[w]; es = wsl[w]; }
      }
      sel[it] = ei;
      cB[es] = 0u;                      // remove winner (real bits always > 0)
    }
    __syncthreads();
  }
  if (threadIdx.x < MIN_POS_TOPK) top10_out[threadIdx.x] = sel[threadIdx.x];
}

// ---------- K3: blocks 0..15 top-10 (inline rescue), 16..31 neg cut (inline rescue) ----------
__global__ __launch_bounds__(1024)
void k_sel(const unsigned* __restrict__ qcb, const int* __restrict__ qci,
           const int* __restrict__ qcnt,
           const unsigned* __restrict__ scb, const int* __restrict__ sci,
           const int* __restrict__ scnt,
           const int* __restrict__ pos_cnt, const int* __restrict__ neg_cnt,
           const float* __restrict__ miou, const float* __restrict__ scores,
           int* __restrict__ num_pos, int* __restrict__ use_fb,
           int* __restrict__ subsample, int* __restrict__ total_samples,
           int* __restrict__ top10,
           unsigned* __restrict__ vbits_out, int* __restrict__ idx_cut) {
  __shared__ unsigned cB[QCAP];
  __shared__ int      cI[QCAP];
  if (blockIdx.x < NB) {
    // ---------- top-10 path ----------
    int b = blockIdx.x;
    int pc = pos_cnt[b], nc = neg_cnt[b];
    int fb = (pc < MIN_POS_TOPK) ? 1 : 0;
    int np = fb ? MIN_POS_TOPK : pc;
    int k = NEG_POS_RATIO * np;
    int sub = (nc > k) ? 1 : 0;
    if (threadIdx.x == 0) {
      num_pos[b] = np; use_fb[b] = fb; subsample[b] = sub;
      total_samples[b] = sub ? (np + k) : (np + nc);
    }
    if (!fb) return;                       // top10 unused by k_loss
    int E = qcnt[b];
    if (E >= MIN_POS_TOPK && E <= QCAP) {
      for (int j = threadIdx.x; j < E; j += 1024) {
        cB[j] = qcb[(size_t)b * QCAP + j];   // all > 0 (q >= QT)
        cI[j] = qci[(size_t)b * QCAP + j];
      }
      __syncthreads();
      argmax10(cB, cI, E, top10 + b * MIN_POS_TOPK);
      return;
    }
    // ---------- inline rescue: adaptive 64-bin re-gather ----------
    const float* mi = miou + (size_t)b * NANCH;
    __shared__ unsigned qh[64];
    __shared__ int s_thr, s_cnt, s_ok;
    if (threadIdx.x < 64) qh[threadIdx.x] = 0u;
    if (threadIdx.x == 0) { s_cnt = 0; s_ok = 0; }
    __syncthreads();
    for (int n = threadIdx.x; n < NANCH; n += 1024) {
      float q = mi[n];
      if (q >= QT) {
        unsigned bin = (unsigned)(q * 64.0f);
        if (bin > 63u) bin = 63u;
        atomicAdd(&qh[bin], 1u);
      }
    }
    __syncthreads();
    if (threadIdx.x == 0) {
      unsigned cum = 0; int t = -1;
      for (int i = 63; i >= 8; --i) {          // largest t with suffix >= 10
        cum += qh[i];
        if (cum >= (unsigned)MIN_POS_TOPK) { t = i; break; }
      }
      if (t < 0) t = 8;
      unsigned c = 0;
      for (int i = t; i < 64; ++i) c += qh[i];
      s_thr = t;
      s_ok = (c >= (unsigned)MIN_POS_TOPK && c <= (unsigned)QCAP) ? 1 : 0;
    }
    __syncthreads();
    if (s_ok) {
      int t = s_thr;
      for (int n = threadIdx.x; n < NANCH; n += 1024) {
        float q = mi[n];
        if (q >= QT) {
          unsigned bin = (unsigned)(q * 64.0f);
          if (bin > 63u) bin = 63u;
          if ((int)bin >= t) {
            int slot = atomicAdd(&s_cnt, 1);
            if (slot < QCAP) {
              cB[slot] = __float_as_uint(q);
              cI[slot] = n;
            }
          }
        }
      }
      __syncthreads();
      int E2 = s_cnt < QCAP ? s_cnt : QCAP;
      argmax10(cB, cI, E2, top10 + b * MIN_POS_TOPK);
    } else {
      // ultra-fallback (structurally ~never): exact 10-iteration full scan
      __shared__ float fsv[16];
      __shared__ int   fsi[16];
      __shared__ int   fsel[MIN_POS_TOPK];
      int lane = threadIdx.x & 63;
      int wid  = threadIdx.x >> 6;
      for (int it = 0; it < MIN_POS_TOPK; ++it) {
        float bv = -1.0f; int bi = NANCH;
        for (int n = threadIdx.x; n < NANCH; n += 1024) {
          bool skip = false;
          for (int s2 = 0; s2 < it; ++s2) if (fsel[s2] == n) skip = true;
          if (skip) continue;
          float v = mi[n];
          if (v > bv || (v == bv && n < bi)) { bv = v; bi = n; }
        }
        #pragma unroll
        for (int m = 32; m >= 1; m >>= 1) {
          float ov = __shfl_xor(bv, m, 64);
          int   oi = __shfl_xor(bi, m, 64);
          if (ov > bv || (ov == bv && oi < bi)) { bv = ov; bi = oi; }
        }
        if (lane == 0) { fsv[wid] = bv; fsi[wid] = bi; }
        __syncthreads();
        if (threadIdx.x == 0) {
          float bb = -1.0f; int bj = NANCH;
          for (int w = 0; w < 16; ++w)
            if (fsv[w] > bb || (fsv[w] == bb && fsi[w] < bj)) { bb = fsv[w]; bj = fsi[w]; }
          fsel[it] = bj;
        }
        __syncthreads();
      }
      if (threadIdx.x < MIN_POS_TOPK) top10[b * MIN_POS_TOPK + threadIdx.x] = fsel[threadIdx.x];
    }
  } else {
    // ---------- neg-cut path ----------
    __shared__ unsigned hist[256];
    __shared__ int s_bkt, s_below, s_cnt, s_fail;
    unsigned* BB = cB;                   // boundary bits list (cap BCAP)
    int*      BI = cI;
    int b = blockIdx.x - NB;
    int pc = pos_cnt[b], nc = neg_cnt[b];
    int np = (pc < MIN_POS_TOPK) ? MIN_POS_TOPK : pc;
    int k = NEG_POS_RATIO * np;
    if (nc <= k) {
      if (threadIdx.x == 0) { vbits_out[b] = 0u; idx_cut[b] = -1; }
      return;
    }
    int E = scnt[b];
    bool cand_ok = (E >= k && E <= SCAP);
    if (threadIdx.x == 0) s_fail = 0;
    if (cand_ok) {
      // exact neg cut via 256-bin sub-hist of [0, ST): s*2^14 exact & monotone
      if (threadIdx.x < 256) hist[threadIdx.x] = 0u;
      if (threadIdx.x == 0) s_cnt = 0;
      __syncthreads();
      for (int j = threadIdx.x; j < E; j += 1024) {
        float s = __uint_as_float(scb[(size_t)b * SCAP + j]);
        unsigned bin = (unsigned)(s * 16384.0f);
        atomicAdd(&hist[bin > 255u ? 255u : bin], 1u);
      }
      __syncthreads();
      if (threadIdx.x == 0) {
        unsigned cum = 0; int bkt = 255;
        for (int t = 0; t < 256; ++t) {
          if (cum + hist[t] >= (unsigned)k) { bkt = t; break; }
          cum += hist[t];
        }
        s_bkt = bkt; s_below = (int)cum;
      }
      __syncthreads();
      int bkt = s_bkt;
      for (int j = threadIdx.x; j < E; j += 1024) {
        unsigned sb = scb[(size_t)b * SCAP + j];
        float s = __uint_as_float(sb);
        unsigned bin = (unsigned)(s * 16384.0f);
        if ((int)(bin > 255u ? 255u : bin) == bkt) {
          int slot = atomicAdd(&s_cnt, 1);
          if (slot < BCAP) { BB[slot] = sb; BI[slot] = sci[(size_t)b * SCAP + j]; }
        }
      }
      __syncthreads();
      int cnt = s_cnt;
      int r = k - s_below;
      if (cnt > BCAP || r < 1 || r > cnt) {
        if (threadIdx.x == 0) s_fail = 1;
      } else {
        for (int e = threadIdx.x; e < cnt; e += 1024) {
          unsigned mb = BB[e]; int mi_ = BI[e];
          int rank = 0;
          for (int j = 0; j < cnt; ++j) {
            unsigned ob = BB[j]; int oi = BI[j];
            rank += (ob < mb || (ob == mb && oi < mi_)) ? 1 : 0;
          }
          if (rank == r - 1) { vbits_out[b] = mb; idx_cut[b] = mi_; }
        }
      }
      __syncthreads();
      if (!s_fail) return;
    }
    // ---------- inline rescue: full-image 256-bin hist ----------
    const float* mi = miou + (size_t)b * NANCH;
    const float* sc = scores + (size_t)b * NANCH;
    if (threadIdx.x < 256) hist[threadIdx.x] = 0u;
    if (threadIdx.x == 0) s_cnt = 0;
    __syncthreads();
    for (int n = threadIdx.x; n < NANCH; n += 1024) {
      if (mi[n] < NEG_THR) {
        unsigned bin = (unsigned)(sc[n] * 256.0f);
        if (bin > 255u) bin = 255u;
        atomicAdd(&hist[bin], 1u);
      }
    }
    __syncthreads();
    if (threadIdx.x == 0) {
      unsigned cum = 0; int bkt = 255;
      for (int t = 0; t < 256; ++t) {
        if (cum + hist[t] >= (unsigned)k) { bkt = t; break; }
        cum += hist[t];
      }
      s_bkt = bkt; s_below = (int)cum;
    }
    __syncthreads();
    int bkt = s_bkt;
    for (int n = threadIdx.x; n < NANCH; n += 1024) {
      if (mi[n] < NEG_THR) {
        float s = sc[n];
        unsigned bin = (unsigned)(s * 256.0f);
        if (bin > 255u) bin = 255u;
        if ((int)bin == bkt) {
          int slot = atomicAdd(&s_cnt, 1);
          if (slot < BCAP) {
            BB[slot] = __float_as_uint(s);
            BI[slot] = n;
          }
        }
      }
    }
    __syncthreads();
    int cnt = s_cnt < BCAP ? s_cnt : BCAP;
    int r = k - s_below;
    if (threadIdx.x == 0 && (r < 1 || r > cnt)) {   // overflow safety (never expected)
      vbits_out[b] = 0xFFFFFFFFu; idx_cut[b] = NANCH;
    }
    for (int e = threadIdx.x; e < cnt; e += 1024) {
      unsigned mb = BB[e]; int mi_ = BI[e];
      int rank = 0;
      for (int j = 0; j < cnt; ++j) {
        unsigned ob = BB[j]; int oi = BI[j];
        rank += (ob < mb || (ob == mb && oi < mi_)) ? 1 : 0;
      }
      if (rank == r - 1) { vbits_out[b] = mb; idx_cut[b] = mi_; }
    }
  }
}

// ---------- K4: per-anchor loss accumulation ----------
__global__ __launch_bounds__(256)
void k_loss(const float* __restrict__ cls, const float* __restrict__ reg,
            const float* __restrict__ anchors, const float* __restrict__ tb,
            const int* __restrict__ tl, const float* __restrict__ scores,
            const float* __restrict__ miou, const int* __restrict__ midx,
            const int* __restrict__ use_fb, const int* __restrict__ top10,
            const int* __restrict__ subsample, const unsigned* __restrict__ vbits,
            const int* __restrict__ idx_cut,
            float* __restrict__ sums /* [NB][3] : pos, neg, reg */) {
  int b = blockIdx.x >> 8;
  int n = ((blockIdx.x & 255) << 8) | threadIdx.x;
  __shared__ int s_top10[MIN_POS_TOPK];
  __shared__ int s_usefb, s_sub, s_cut;
  __shared__ unsigned s_vb;
  __shared__ float accp, accn, accr;
  if (threadIdx.x < MIN_POS_TOPK) s_top10[threadIdx.x] = top10[b * MIN_POS_TOPK + threadIdx.x];
  if (threadIdx.x == 0) {
    s_usefb = use_fb[b]; s_sub = subsample[b]; s_cut = idx_cut[b]; s_vb = vbits[b];
    accp = 0.0f; accn = 0.0f; accr = 0.0f;
  }
  __syncthreads();

  size_t idx = (size_t)b * NANCH + n;
  float mi = miou[idx];

  bool pos;
  if (s_usefb) {
    pos = false;
    #pragma unroll
    for (int i = 0; i < MIN_POS_TOPK; ++i) pos |= (s_top10[i] == n);
  } else {
    pos = (mi >= POS_THR);
  }
  bool neg = (mi < NEG_THR);
  bool nsel = false;
  if (neg) {
    if (!s_sub) nsel = true;
    else {
      unsigned sb = __float_as_uint(scores[idx]);
      nsel = (sb < s_vb) || (sb == s_vb && n <= s_cut);
    }
  }

  float cp = 0.0f, cn = 0.0f, rg = 0.0f;
  if (pos || nsel) {
    int mx = 0, t = 0;
    if (pos) { mx = midx[idx]; t = tl[b * NM + mx]; }
    size_t cb = ((size_t)b * NC) * NANCH + n;
    float mxl = -3.0e38f, l0 = 0.0f, lt = 0.0f;
    for (int c = 0; c < NC; ++c) {
      float l = cls[cb + (size_t)c * NANCH];
      if (c == 0) l0 = l;
      if (c == t) lt = l;
      mxl = fmaxf(mxl, l);
    }
    float se = 0.0f;
    for (int c = 0; c < NC; ++c) {
      float l = cls[cb + (size_t)c * NANCH];
      se += expf(l - mxl);
    }
    float lse = mxl + logf(se);
    if (nsel) {
      float ce = lse - l0;
      float pt = expf(-ce);
      float om = 1.0f - pt;
      cn = F_ALPHA * om * om * ce;
    }
    if (pos) {
      float ce = lse - lt;
      float pt = expf(-ce);
      float om = 1.0f - pt;
      cp = F_ALPHA * om * om * ce;
      // decode + GIoU vs matched GT
      const float4 a4 = ((const float4*)anchors)[n];
      float aw = a4.z - a4.x, ah = a4.w - a4.y;
      float acx = a4.x + 0.5f * aw, acy = a4.y + 0.5f * ah;
      size_t rb = ((size_t)b * 4) * NANCH + n;
      float rx = reg[rb];
      float ry = reg[rb + (size_t)NANCH];
      float rw = reg[rb + 2 * (size_t)NANCH];
      float rh = reg[rb + 3 * (size_t)NANCH];
      float ccx = acx + rx * aw, ccy = acy + ry * ah;
      float w = aw * expf(rw), h = ah * expf(rh);
      float d0 = ccx - 0.5f * w, d1 = ccy - 0.5f * h;
      float d2 = ccx + 0.5f * w, d3 = ccy + 0.5f * h;
      const float* g = tb + ((size_t)b * NM + mx) * 4;
      float gx1 = g[0], gy1 = g[1], gx2 = g[2], gy2 = g[3];
      float area_a = (d2 - d0) * (d3 - d1);
      float area_b = (gx2 - gx1) * (gy2 - gy1);
      float lx = fmaxf(d0, gx1), ly = fmaxf(d1, gy1);
      float rx2 = fminf(d2, gx2), ry2 = fminf(d3, gy2);
      float iw = fmaxf(rx2 - lx, 0.0f), ih = fmaxf(ry2 - ly, 0.0f);
      float inter = iw * ih;
      float uni = area_a + area_b - inter;
      float iou = inter / fmaxf(uni, 1e-7f);
      float ex1 = fminf(d0, gx1), ey1 = fminf(d1, gy1);
      float ex2 = fmaxf(d2, gx2), ey2 = fmaxf(d3, gy2);
      float ew = fmaxf(ex2 - ex1, 0.0f), eh = fmaxf(ey2 - ey1, 0.0f);
      float enc = ew * eh;
      float giou = iou - (enc - uni) / fmaxf(enc, 1e-7f);
      rg = 1.0f - giou;
    }
  }

  if (cp != 0.0f) atomicAdd(&accp, cp);
  if (cn != 0.0f) atomicAdd(&accn, cn);
  if (rg != 0.0f) atomicAdd(&accr, rg);
  __syncthreads();
  if (threadIdx.x == 0) {
    if (accp != 0.0f) atomicAdd(&sums[b * 3 + 0], accp);
    if (accn != 0.0f) atomicAdd(&sums[b * 3 + 1], accn);
    if (accr != 0.0f) atomicAdd(&sums[b * 3 + 2], accr);
  }
}

// ---------- K5: finalize (parallel, 64 threads) ----------
__global__ void k_final(const float* __restrict__ sums,
                        const int* __restrict__ total_samples,
                        const int* __restrict__ num_pos,
                        float* __restrict__ out) {
  int t = threadIdx.x;
  float cm = 0.0f, rm = 0.0f;
  if (t < NB) {
    int ts = total_samples[t]; if (ts < 1) ts = 1;
    int np = num_pos[t]; if (np < 1) np = 1;
    cm = (sums[t * 3 + 0] + sums[t * 3 + 1]) / (float)ts;
    rm = sums[t * 3 + 2] / (float)np;
  }
  #pragma unroll
  for (int m = 8; m >= 1; m >>= 1) {
    cm += __shfl_down(cm, m, 64);
    rm += __shfl_down(rm, m, 64);
  }
  if (t == 0) out[0] = cm / (float)NB + rm / (float)NB;
}

extern "C" void kernel_launch(void* const* d_in, const int* in_sizes, int n_in,
                              void* d_out, int out_size, void* d_ws, size_t ws_size,
                              hipStream_t stream) {
  const float* cls     = (const float*)d_in[0];
  const float* reg     = (const float*)d_in[1];
  const float* anchors = (const float*)d_in[2];
  const float* tb      = (const float*)d_in[3];
  const int*   tl      = (const int*)d_in[4];
  const float* scores  = (const float*)d_in[5];
  float* out = (float*)d_out;

  char* ws = (char*)d_ws;
  size_t off = 0;
  float* miou = (float*)(ws + off);            off += (size_t)4 * NB * NANCH;
  int*   midx = (int*)(ws + off);              off += (size_t)4 * NB * NANCH;
  unsigned* qcb = (unsigned*)(ws + off);       off += (size_t)4 * NB * QCAP;
  int*   qci = (int*)(ws + off);               off += (size_t)4 * NB * QCAP;
  unsigned* scb = (unsigned*)(ws + off);       off += (size_t)4 * NB * SCAP;
  int*   sci = (int*)(ws + off);               off += (size_t)4 * NB * SCAP;
  int* scal = (int*)(ws + off);
  // zeroed by k_iou block 0: first 4*NB ints + sums (3*NB floats)
  int* pos_cnt  = scal;
  int* neg_cnt  = scal + NB;
  int* qcnt     = scal + 2 * NB;
  int* scnt     = scal + 3 * NB;
  int* num_pos       = scal + 4 * NB;
  int* use_fb        = scal + 5 * NB;
  int* subsample     = scal + 6 * NB;
  int* idx_cut       = scal + 7 * NB;
  unsigned* vbits    = (unsigned*)(scal + 8 * NB);
  int* total_samples = scal + 9 * NB;
  int* top10         = scal + 10 * NB;                         // NB*10
  float* sums        = (float*)(scal + 10 * NB + MIN_POS_TOPK * NB); // NB*3

  k_iou<<<NB * 128, IOU_TPB, 0, stream>>>(reg, anchors, tb, miou, midx,
                                          scal, sums);
  k_gather<<<NB * 64, 1024, 0, stream>>>(miou, scores, pos_cnt, neg_cnt,
                                         qcb, qci, qcnt, scb, sci, scnt);
  k_sel<<<2 * NB, 1024, 0, stream>>>(qcb, qci, qcnt, scb, sci, scnt,
                                     pos_cnt, neg_cnt, miou, scores,
                                     num_pos, use_fb, subsample, total_samples,
                                     top10, vbits, idx_cut);
  k_loss<<<NB * 256, 256, 0, stream>>>(cls, reg, anchors, tb, tl, scores,
                                       miou, midx, use_fb, top10, subsample,
                                       vbits, idx_cut, sums);
  k_final<<<1, 64, 0, stream>>>(sums, total_samples, num_pos, out);
}